// Round 4
// baseline (1685.768 us; speedup 1.0000x reference)
//
#include <hip/hip_runtime.h>

// ---------------------------------------------------------------------------
// Two-layer tanh RNN — persistent cluster kernel, round 6: readlane dot phase.
// B=64, T=512, H=512, I=128, W_OUT=32. fp32 in/out, f16-pair internal, fp32 acc.
//
// 256 WGs x 1024 threads, 1 WG/CU. cluster cl = gid&63 (layer=cl>>5, pair=cl&31),
// sibling s = gid>>6; gid%8 == cl%8 => cluster + other-layer cluster co-XCD.
//
// Round-6 change (dot phase was LDS-instruction-bound: 512 b128/CU/step x
// ~8-12cy pipe occupancy ~= 2/3 of the step):
//   h lives in a flat LDS array hv2[pair][batch] (dwords). Each wave reads its
//   whole chunk ONCE via a single distributed ds_read_b64 (lane j holds pair-
//   word j of both batches), then broadcasts via v_readlane -> SGPR -> v_dot2.
//   LDS instrs in dots: 512 -> 16 per CU per step; VALU ~2 instr/pair (issue-
//   bound ~2048 cy/SIMD for L1).
// Everything else as round 5: psum[8][2][128] cross-wave reduce, lanes 0-255
// finish rows (tanh+pack+post, own pairs direct to LDS), sibling quarters via
// tagged 64-bit {tag|f16pair} atoms (RELAXED agent scope), L1 prefetches
// h0(t+1) at top of step, L0 ring-overwrite throttle, setprio around compute,
// FC epilogue in L1 s==0.
// ---------------------------------------------------------------------------

#define T_STEPS 512
#define NBATCH  64
#define DRING   256
#define THR_LEAD 192

typedef _Float16 half2v __attribute__((ext_vector_type(2)));

__device__ __forceinline__ unsigned pack2(float a, float b) {
    _Float16 fa = (_Float16)a, fb = (_Float16)b;
    unsigned short ua = __builtin_bit_cast(unsigned short, fa);
    unsigned short ub = __builtin_bit_cast(unsigned short, fb);
    return (unsigned)ua | ((unsigned)ub << 16);
}

__device__ __forceinline__ float dot2acc(unsigned w, unsigned h, float acc) {
#if __has_builtin(__builtin_amdgcn_fdot2)
    return __builtin_amdgcn_fdot2(__builtin_bit_cast(half2v, w),
                                  __builtin_bit_cast(half2v, h), acc, false);
#else
    half2v wv = __builtin_bit_cast(half2v, w);
    half2v hv = __builtin_bit_cast(half2v, h);
    acc = fmaf((float)wv.x, (float)hv.x, acc);
    return fmaf((float)wv.y, (float)hv.y, acc);
#endif
}

__device__ __forceinline__ float fast_tanh(float xv) {
    float e2 = __builtin_amdgcn_exp2f(xv * 2.885390082f);
    return 1.f - 2.f * __builtin_amdgcn_rcpf(e2 + 1.f);
}

// Poll N tagged atoms concurrently, relaxed agent scope.
template <int N>
__device__ __forceinline__ void pollN(unsigned long long* const (&p)[N],
                                      const unsigned (&tag)[N],
                                      unsigned (&res)[N], long& budget) {
    bool done[N];
#pragma unroll
    for (int i = 0; i < N; ++i) done[i] = false;
    int remaining = N;
    while (remaining > 0 && budget > 0) {
        unsigned long long v[N];
#pragma unroll
        for (int i = 0; i < N; ++i)
            if (!done[i])
                v[i] = __hip_atomic_load(p[i], __ATOMIC_RELAXED, __HIP_MEMORY_SCOPE_AGENT);
#pragma unroll
        for (int i = 0; i < N; ++i)
            if (!done[i] && (unsigned)(v[i] >> 32) == tag[i]) {
                res[i] = (unsigned)v[i]; done[i] = true; --remaining;
            }
        --budget;
    }
}

// Packed-weight layouts [s<4][j<PW][lane<1024].
// r = s*128 + (L&127), c = L>>7 (8 chunks), k = c*(K/8) + 2*j.
#define N0 (4 * 40 * 1024)
#define N1 (4 * 64 * 1024)

__global__ void init_pack(const float* __restrict__ Wih0, const float* __restrict__ Whh0,
                          const float* __restrict__ Wih1, const float* __restrict__ Whh1,
                          unsigned* __restrict__ wp0, unsigned* __restrict__ wp1) {
    int gid = blockIdx.x * 256 + threadIdx.x;
    if (gid < N0) {
        int L = gid & 1023; int rest = gid >> 10; int j = rest % 40; int s = rest / 40;
        int r = s * 128 + (L & 127); int c = L >> 7; int k = c * 80 + 2 * j;
        float w0 = (k < 128)     ? Wih0[r * 128 + k]     : Whh0[r * 512 + (k - 128)];
        float w1 = (k + 1 < 128) ? Wih0[r * 128 + k + 1] : Whh0[r * 512 + (k - 127)];
        wp0[gid] = pack2(w0, w1);
    } else {
        int g2 = gid - N0;
        if (g2 < N1) {
            int L = g2 & 1023; int rest = g2 >> 10; int j = rest % 64; int s = rest / 64;
            int r = s * 128 + (L & 127); int c = L >> 7; int k = c * 128 + 2 * j;
            float w0 = (k < 512)     ? Wih1[r * 512 + k]     : Whh1[r * 512 + (k - 512)];
            float w1 = (k + 1 < 512) ? Wih1[r * 512 + k + 1] : Whh1[r * 512 + (k - 511)];
            wp1[g2] = pack2(w0, w1);
        }
    }
}

// PW: f16-pairs per lane per chunk (40 for L0, 64 for L1). p-space (pair words):
//   L0: p<64 = x pairs, p=64+pr = h0 pairs (pr<256). NPAIR=320. wreg[j] <-> p=40c+j.
//   L1: p<256 = h0 pairs, p=256+pr = h1 pairs.      NPAIR=512. wreg[j] <-> p=64c+j.
template <int PW, int LAYER>
__device__ __forceinline__ void run_layer(
    int b0, int s, int L, int pair,
    const float* __restrict__ x, const float* __restrict__ noise,
    const unsigned* __restrict__ wpack,
    const float* __restrict__ bih, const float* __restrict__ bhh,
    unsigned long long* __restrict__ hbuf0,
    unsigned long long* __restrict__ hbuf1,
    int* __restrict__ prog,
    const float* __restrict__ fcw, const float* __restrict__ fcb,
    float* __restrict__ out) {
    constexpr int NPAIR = 8 * PW;
    const int c = L >> 7;                // chunk 0..7 (wave-uniform: 2 waves/chunk)
    const int rw = L & 127;              // row within this WG's quarter
    const int lane = L & 63;

    unsigned wreg[PW];
#pragma unroll
    for (int j = 0; j < PW; ++j) {
        wreg[j] = wpack[(s * PW + j) * 1024 + L];
        asm volatile("" : "+v"(wreg[j]));
    }

    __shared__ __align__(16) unsigned hv2[2 * NPAIR];   // [pair][batch] dwords
    __shared__ float psum[8][2][128];                   // [chunk][batch][row]
    for (int i = L; i < 2 * NPAIR; i += 1024) hv2[i] = 0u;  // h(-1)=0

    long budget = 2000000000L;           // hang bailout only

    float cb = 0.f;
    float nz[2] = {0.f, 0.f};
    if (L < 256) {                       // reduce-role constants (row = s*128+(L&127))
        int rr = s * 128 + (L & 127);
        cb = bih[rr] + bhh[rr];
#pragma unroll
        for (int bb = 0; bb < 2; ++bb)
            nz[bb] = noise[(((size_t)(b0 + bb) * T_STEPS) * 2 + LAYER) * 512 + rr];
    }

    __syncthreads();                     // zero-fill done

    // t=0 inputs
    if constexpr (LAYER == 0) {
        if (L >= 640 && L < 768) {
            int idx = L - 640; int xb = idx >> 6; int j = idx & 63;
            float2 xf = *(const float2*)(x + ((size_t)(b0 + xb) * T_STEPS) * 128 + 2 * j);
            hv2[2 * j + xb] = pack2(xf.x, xf.y);
        }
    } else {
        if (L == 0 && s == 0)            // reset progress before any L0 throttle read
            __hip_atomic_store(&prog[pair], 0, __ATOMIC_RELAXED, __HIP_MEMORY_SCOPE_AGENT);
        if (L >= 512) {
            int idx = L - 512; int bb = idx >> 8; int p0 = idx & 255;
            unsigned long long* p[1]; unsigned tg[1], res[1];
            p[0] = &hbuf0[((size_t)0 * NBATCH + (b0 + bb)) * 256 + p0];
            tg[0] = 1u;
            pollN<1>(p, tg, res, budget);
            hv2[2 * p0 + bb] = res[0];
        }
    }
    __syncthreads();

    int known = 0;

    for (int t = 0; t < T_STEPS; ++t) {
        __builtin_amdgcn_s_setprio(1);
        const bool last = (t == T_STEPS - 1);

        // ---- top-of-step prefetches (RTTs overlap the dot phase) ----
        unsigned long long pf = 0;
        if constexpr (LAYER == 1) {
            if (!last && L >= 512) {     // h0(t+1): L0 leads, tag usually already set
                int idx = L - 512; int bb = idx >> 8; int p0 = idx & 255;
                pf = __hip_atomic_load(
                    &hbuf0[((size_t)((t + 1) & (DRING - 1)) * NBATCH + (b0 + bb)) * 256 + p0],
                    __ATOMIC_RELAXED, __HIP_MEMORY_SCOPE_AGENT);
            }
        }
        float2 xf;
        if constexpr (LAYER == 0) {
            if (!last && L >= 640 && L < 768) {
                int idx = L - 640; int xb = idx >> 6; int j = idx & 63;
                xf = *(const float2*)(x + ((size_t)(b0 + xb) * T_STEPS + (t + 1)) * 128 + 2 * j);
            }
        }
        float nznext[2] = {0.f, 0.f};
        if (!last && L < 256) {
            int rr = s * 128 + (L & 127);
#pragma unroll
            for (int bb = 0; bb < 2; ++bb)
                nznext[bb] = noise[(((size_t)(b0 + bb) * T_STEPS + (t + 1)) * 2 + LAYER) * 512 + rr];
        }

        // ---- L0 ring-overwrite throttle (lead cap 192 < horizon 257) ----
        if constexpr (LAYER == 0) {
            if (t - known > THR_LEAD) {
                __builtin_amdgcn_s_setprio(0);
                while (t - known > THR_LEAD && budget > 0) {
                    known = __hip_atomic_load(&prog[pair], __ATOMIC_RELAXED,
                                              __HIP_MEMORY_SCOPE_AGENT);
                    --budget;
                }
                __builtin_amdgcn_s_setprio(1);
            }
        }

        // ---- dots: one ds_read_b64 per wave, then readlane->SGPR->dot2 ----
        {
            const int pidx = PW * c + (lane < PW ? lane : PW - 1);
            uint2 hw = *(const uint2*)(&hv2[2 * pidx]);   // lane j: pair-word PW*c+j, both batches
            float a00 = 0.f, a01 = 0.f, a02 = 0.f, a03 = 0.f;
            float a10 = 0.f, a11 = 0.f, a12 = 0.f, a13 = 0.f;
#pragma unroll
            for (int j = 0; j < PW; j += 4) {
                unsigned s00 = __builtin_amdgcn_readlane(hw.x, j + 0);
                unsigned s10 = __builtin_amdgcn_readlane(hw.y, j + 0);
                unsigned s01 = __builtin_amdgcn_readlane(hw.x, j + 1);
                unsigned s11 = __builtin_amdgcn_readlane(hw.y, j + 1);
                unsigned s02 = __builtin_amdgcn_readlane(hw.x, j + 2);
                unsigned s12 = __builtin_amdgcn_readlane(hw.y, j + 2);
                unsigned s03 = __builtin_amdgcn_readlane(hw.x, j + 3);
                unsigned s13 = __builtin_amdgcn_readlane(hw.y, j + 3);
                a00 = dot2acc(wreg[j + 0], s00, a00);
                a10 = dot2acc(wreg[j + 0], s10, a10);
                a01 = dot2acc(wreg[j + 1], s01, a01);
                a11 = dot2acc(wreg[j + 1], s11, a11);
                a02 = dot2acc(wreg[j + 2], s02, a02);
                a12 = dot2acc(wreg[j + 2], s12, a12);
                a03 = dot2acc(wreg[j + 3], s03, a03);
                a13 = dot2acc(wreg[j + 3], s13, a13);
            }
            psum[c][0][rw] = (a00 + a01) + (a02 + a03);
            psum[c][1][rw] = (a10 + a11) + (a12 + a13);
        }

        __syncthreads();                 // barrier 1: psum ready, hv2 reads done

        // ---- reduce + tanh + post + own-LDS write: lanes 0..255 ----
        if (L < 256) {
            int bb = L >> 7; int rr = L & 127;
            float s8 = ((psum[0][bb][rr] + psum[1][bb][rr]) +
                        (psum[2][bb][rr] + psum[3][bb][rr])) +
                       ((psum[4][bb][rr] + psum[5][bb][rr]) +
                        (psum[6][bb][rr] + psum[7][bb][rr]));
            float nzsel = (bb == 0) ? nz[0] : nz[1];
            float h = fast_tanh(s8 + cb + nzsel);
            float hnb = __shfl_down(h, 1);
            if ((L & 1) == 0) {
                unsigned pv = pack2(h, hnb);
                int pr = s * 64 + (rr >> 1);            // global pair 0..255
                unsigned long long atom =
                    ((unsigned long long)(unsigned)(t + 1) << 32) | (unsigned long long)pv;
                if constexpr (LAYER == 0)
                    __hip_atomic_store(
                        &hbuf0[((size_t)(t & (DRING - 1)) * NBATCH + (b0 + bb)) * 256 + pr],
                        atom, __ATOMIC_RELAXED, __HIP_MEMORY_SCOPE_AGENT);
                else
                    __hip_atomic_store(
                        &hbuf1[((size_t)(t & 3) * NBATCH + (b0 + bb)) * 256 + pr],
                        atom, __ATOMIC_RELAXED, __HIP_MEMORY_SCOPE_AGENT);
                int q = (LAYER == 0 ? 64 : 256) + pr;   // own pairs direct to LDS
                hv2[2 * q + bb] = pv;
            }
        }

        __builtin_amdgcn_s_setprio(0);
        if (last) break;

        nz[0] = nznext[0]; nz[1] = nznext[1];

        // ---- gather sibling quarters (+x / +h0) into hv2 ----
        if constexpr (LAYER == 0) {
            if (L >= 256 && L < 640) {   // 384 lanes: 3 sib quarters x 2 batches
                int idx = L - 256; int bb = idx / 192; int m = idx % 192;
                int p2 = (m < s * 64) ? m : m + 64;
                unsigned long long* p[1]; unsigned tg[1], res[1];
                p[0] = &hbuf0[((size_t)(t & (DRING - 1)) * NBATCH + (b0 + bb)) * 256 + p2];
                tg[0] = (unsigned)(t + 1);
                pollN<1>(p, tg, res, budget);
                hv2[2 * (64 + p2) + bb] = res[0];
            }
            if (L >= 640 && L < 768) {   // x(t+1) pairs
                int idx = L - 640; int xb = idx >> 6; int j = idx & 63;
                hv2[2 * j + xb] = pack2(xf.x, xf.y);
            }
        } else {
            if (L >= 128 && L < 512) {   // 384 lanes: h1 sib quarters
                int idx = L - 128; int bb = idx / 192; int m = idx % 192;
                int p2 = (m < s * 64) ? m : m + 64;
                unsigned long long* p[1]; unsigned tg[1], res[1];
                p[0] = &hbuf1[((size_t)(t & 3) * NBATCH + (b0 + bb)) * 256 + p2];
                tg[0] = (unsigned)(t + 1);
                pollN<1>(p, tg, res, budget);
                hv2[2 * (256 + p2) + bb] = res[0];
            }
            if (L >= 512) {              // h0(t+1): check prefetch, else poll
                int idx = L - 512; int bb = idx >> 8; int p0 = idx & 255;
                unsigned long long v = pf;
                unsigned long long* ptr =
                    &hbuf0[((size_t)((t + 1) & (DRING - 1)) * NBATCH + (b0 + bb)) * 256 + p0];
                while ((unsigned)(v >> 32) != (unsigned)(t + 2) && budget > 0) {
                    v = __hip_atomic_load(ptr, __ATOMIC_RELAXED, __HIP_MEMORY_SCOPE_AGENT);
                    --budget;
                }
                hv2[2 * p0 + bb] = (unsigned)v;
            }
        }
        __syncthreads();                 // barrier 2: hv2(t+1) complete

        // prog = t-1: all sibs provably consumed h0 slot t&255 by now
        if constexpr (LAYER == 1) {
            if (L == 0 && s == 0 && t > 0)
                __hip_atomic_store(&prog[pair], t - 1, __ATOMIC_RELAXED,
                                   __HIP_MEMORY_SCOPE_AGENT);
        }
    }

    __builtin_amdgcn_s_setprio(0);

    if constexpr (LAYER == 1) {
        if (s == 0) {                    // FC epilogue: out = h1(T-1) @ fc_w^T + fc_b
            __shared__ float hs[2][512];
            __shared__ float part[2][512];
            if (L < 512) {
                int bb = L >> 8; int pr = L & 255;
                unsigned long long* p[1]; unsigned tg[1], res[1];
                p[0] = &hbuf1[((size_t)((T_STEPS - 1) & 3) * NBATCH + (b0 + bb)) * 256 + pr];
                tg[0] = (unsigned)T_STEPS;
                pollN<1>(p, tg, res, budget);
                half2v h2 = __builtin_bit_cast(half2v, res[0]);
                hs[bb][2 * pr] = (float)h2.x; hs[bb][2 * pr + 1] = (float)h2.y;
            }
            __syncthreads();
            {
                int bb = L >> 9; int rest = L & 511; int o = rest & 31; int seg = rest >> 5;
                const float* wr = fcw + o * 512 + seg * 32;
                const float* hr = &hs[bb][seg * 32];
                float a = 0.f;
#pragma unroll
                for (int k = 0; k < 32; ++k) a = fmaf(wr[k], hr[k], a);
                part[bb][rest] = a;
            }
            __syncthreads();
            if (L < 64) {
                int bb = L >> 5; int o = L & 31;
                float ssum = fcb[o];
#pragma unroll
                for (int sgi = 0; sgi < 16; ++sgi) ssum += part[bb][sgi * 32 + o];
                out[(b0 + bb) * 32 + o] = ssum;
            }
        }
    }
}

__global__ __launch_bounds__(1024, 4)
void rnn_dual(const float* __restrict__ x, const float* __restrict__ noise,
              const unsigned* __restrict__ wp0, const unsigned* __restrict__ wp1,
              const float* __restrict__ bih0, const float* __restrict__ bhh0,
              const float* __restrict__ bih1, const float* __restrict__ bhh1,
              const float* __restrict__ fcw, const float* __restrict__ fcb,
              unsigned long long* __restrict__ hbuf0,
              unsigned long long* __restrict__ hbuf1,
              int* __restrict__ prog,
              float* __restrict__ out) {
    const int L = threadIdx.x;
    const int gid = blockIdx.x;
    const int cl = gid & 63;             // cluster: layer*32 + pair
    const int s = gid >> 6;              // sibling quarter 0..3
    const int layer = cl >> 5;
    const int pair = cl & 31;
    const int b0 = pair * 2;             // gid%8 == cl%8: cluster+other-layer co-XCD
    if (layer == 0)
        run_layer<40, 0>(b0, s, L, pair, x, noise, wp0, bih0, bhh0,
                         hbuf0, hbuf1, prog, nullptr, nullptr, nullptr);
    else
        run_layer<64, 1>(b0, s, L, pair, x, noise, wp1, bih1, bhh1,
                         hbuf0, hbuf1, prog, fcw, fcb, out);
}

extern "C" void kernel_launch(void* const* d_in, const int* in_sizes, int n_in,
                              void* d_out, int out_size, void* d_ws, size_t ws_size,
                              hipStream_t stream) {
    const float* x     = (const float*)d_in[0];
    const float* noise = (const float*)d_in[1];
    const float* Wih0  = (const float*)d_in[2];
    const float* Wih1  = (const float*)d_in[3];
    const float* Whh0  = (const float*)d_in[4];
    const float* Whh1  = (const float*)d_in[5];
    const float* bih0  = (const float*)d_in[6];
    const float* bih1  = (const float*)d_in[7];
    const float* bhh0  = (const float*)d_in[8];
    const float* bhh1  = (const float*)d_in[9];
    const float* fcw   = (const float*)d_in[10];
    const float* fcb   = (const float*)d_in[11];
    float* out = (float*)d_out;

    char* ws = (char*)d_ws;
    size_t o = 0;
    unsigned* wp0 = (unsigned*)(ws + o); o += (size_t)N0 * 4;   // 640 KB
    unsigned* wp1 = (unsigned*)(ws + o); o += (size_t)N1 * 4;   // 1 MB
    unsigned long long* hb0 = (unsigned long long*)(ws + o);
    o += (size_t)DRING * NBATCH * 256 * 8;                      // 33.5 MB ring
    unsigned long long* hb1 = (unsigned long long*)(ws + o);
    o += (size_t)4 * NBATCH * 256 * 8;                          // 512 KB ring
    int* prog = (int*)(ws + o); o += 32 * sizeof(int);          // L1 progress

    const int initBlocks = (N0 + N1 + 255) / 256;
    init_pack<<<initBlocks, 256, 0, stream>>>(Wih0, Whh0, Wih1, Whh1, wp0, wp1);
    rnn_dual<<<256, 1024, 0, stream>>>(x, noise, wp0, wp1, bih0, bhh0, bih1, bhh1,
                                       fcw, fcb, hb0, hb1, prog, out);
}